// Round 7
// baseline (757.260 us; speedup 1.0000x reference)
//
#include <hip/hip_runtime.h>
#include <math.h>

// ===========================================================================
// Shared epilogue: 3x3 symmetric Jacobi eigensolve (double) + output writes.
// acc layout (13 floats): [0..2]=sum f  [3..5]=sum r x f
//                         [6..11]=sum rr^T (xx,yy,zz,xy,xz,yz)  [12]=count
// ===========================================================================
__device__ __forceinline__ void frag_epilogue(
    const float* a, int f, int n_frag, const int* __restrict__ frag_sizes,
    float* __restrict__ out)
{
    float cntf  = a[12];
    float denom = fmaxf(cntf, 1.0f);
    float vfx = a[0] / denom, vfy = a[1] / denom, vfz = a[2] / denom;

    double tq0 = (double)a[3], tq1 = (double)a[4], tq2 = (double)a[5];
    double Mxx = (double)a[6], Myy = (double)a[7], Mzz = (double)a[8];
    double Mxy = (double)a[9], Mxz = (double)a[10], Myz = (double)a[11];
    double tr = Mxx + Myy + Mzz;

    double A[3][3] = {
        { tr - Mxx, -Mxy,     -Mxz     },
        { -Mxy,     tr - Myy, -Myz     },
        { -Mxz,     -Myz,     tr - Mzz }
    };
    double V[3][3] = {{1,0,0},{0,1,0},{0,0,1}};

    for (int sweep = 0; sweep < 6; ++sweep) {
        for (int pq = 0; pq < 3; ++pq) {
            int p = (pq == 2) ? 1 : 0;
            int q = (pq == 0) ? 1 : 2;
            double apq = A[p][q];
            if (fabs(apq) <= 1e-14 * (fabs(A[p][p]) + fabs(A[q][q])) ||
                fabs(apq) < 1e-300) continue;
            double theta = (A[q][q] - A[p][p]) / (2.0 * apq);
            double tt;
            if (fabs(theta) > 1e100) tt = 1.0 / (2.0 * theta);
            else tt = copysign(1.0, theta) / (fabs(theta) + sqrt(theta * theta + 1.0));
            double c = 1.0 / sqrt(tt * tt + 1.0);
            double s = tt * c;
            double app = A[p][p], aqq = A[q][q];
            A[p][p] = app - tt * apq;
            A[q][q] = aqq + tt * apq;
            A[p][q] = 0.0; A[q][p] = 0.0;
            int r = 3 - p - q;
            double arp = A[r][p], arq = A[r][q];
            A[r][p] = c * arp - s * arq; A[p][r] = A[r][p];
            A[r][q] = s * arp + c * arq; A[q][r] = A[r][q];
            for (int i2 = 0; i2 < 3; ++i2) {
                double vip = V[i2][p], viq = V[i2][q];
                V[i2][p] = c * vip - s * viq;
                V[i2][q] = s * vip + c * viq;
            }
        }
    }

    double lam0 = A[0][0], lam1 = A[1][1], lam2 = A[2][2];
    double maxeig = fmax(fmax(fmax(lam0, lam1), lam2), 1e-8);
    double thr = 0.01 * maxeig;
    bool small_frag = (frag_sizes[f] <= 1);
    double o0 = (!small_frag && lam0 > thr) ? 1.0 : 0.0;
    double o1 = (!small_frag && lam1 > thr) ? 1.0 : 0.0;
    double o2 = (!small_frag && lam2 > thr) ? 1.0 : 0.0;

    double te0 = V[0][0]*tq0 + V[1][0]*tq1 + V[2][0]*tq2;
    double te1 = V[0][1]*tq0 + V[1][1]*tq1 + V[2][1]*tq2;
    double te2 = V[0][2]*tq0 + V[1][2]*tq1 + V[2][2]*tq2;
    double we0 = te0 / fmax(lam0, 1e-6) * o0;
    double we1 = te1 / fmax(lam1, 1e-6) * o1;
    double we2 = te2 / fmax(lam2, 1e-6) * o2;
    double w0 = V[0][0]*we0 + V[0][1]*we1 + V[0][2]*we2;
    double w1 = V[1][0]*we0 + V[1][1]*we1 + V[1][2]*we2;
    double w2 = V[2][0]*we0 + V[2][1]*we1 + V[2][2]*we2;

    size_t F = (size_t)n_frag;
    out[(size_t)f*3 + 0] = vfx;
    out[(size_t)f*3 + 1] = vfy;
    out[(size_t)f*3 + 2] = vfz;
    out[F*3 + (size_t)f*3 + 0] = (float)w0;
    out[F*3 + (size_t)f*3 + 1] = (float)w1;
    out[F*3 + (size_t)f*3 + 2] = (float)w2;

    float* P = out + F*6 + (size_t)f*9;
    #pragma unroll
    for (int i2 = 0; i2 < 3; ++i2)
        #pragma unroll
        for (int k = 0; k < 3; ++k)
            P[i2*3 + k] = (float)(V[i2][0]*o0*V[k][0] + V[i2][1]*o1*V[k][1]
                                  + V[i2][2]*o2*V[k][2]);
}

// ===========================================================================
// FAST PATH (round 7): deterministic two-pass binning — ZERO global atomics.
//  k0 count_atoms  : per-block LDS hist over 2048 buckets -> histrows row
//  k1 scan_cols    : column scan -> per-(block,bucket) exclusive offsets
//  k2 scan_base    : exclusive scan of bucket totals -> bucket_base[2049]
//  k3 scatter_atoms: re-rank in LDS, scatter 32 B records at exact offsets
//                    (TILE 8 -> 1954 blocks, ~30 waves/CU for store overlap)
//  k4 sort_reduce  : per-bucket LDS counting sort (stride-7: conflict-free)
//                    + 2-lane/frag accumulate + fused f64 Jacobi epilogue
// ===========================================================================
#define NBK  2048            // bucket slots (used: nbk = ceil(F/98) = 2041)
#define FPB  98              // fragments per bucket
#define CAP2 2272            // LDS sort chunk capacity (records)
#define TILE 8
#define APB  (256 * TILE)    // 2048 atoms per bin block
#define MAXPT 9              // ceil(CAP2/256)

__global__ __launch_bounds__(256) void count_atoms(
    const int* __restrict__ frag_id,
    unsigned*  __restrict__ histrows,
    int n_atom)
{
    __shared__ unsigned hist[NBK];
    int t = threadIdx.x;
    for (int b = t; b < NBK; b += 256) hist[b] = 0;
    __syncthreads();
    int bs = blockIdx.x * APB;
    #pragma unroll
    for (int j = 0; j < TILE; ++j) {
        int i = bs + j * 256 + t;
        if (i < n_atom) atomicAdd(&hist[frag_id[i] / FPB], 1u);
    }
    __syncthreads();
    unsigned* row = histrows + (size_t)blockIdx.x * NBK;
    for (int b = t; b < NBK; b += 256) row[b] = hist[b];
}

// One thread per bucket column: exclusive scan down the block rows.
__global__ __launch_bounds__(256) void scan_cols(
    unsigned* __restrict__ histrows,
    unsigned* __restrict__ totals,
    int nblk)
{
    int b = blockIdx.x * 256 + threadIdx.x;
    if (b >= NBK) return;
    unsigned cum = 0;
    for (int k = 0; k < nblk; ++k) {
        size_t idx = (size_t)k * NBK + b;
        unsigned v = histrows[idx];
        histrows[idx] = cum;
        cum += v;
    }
    totals[b] = cum;
}

// Single block: exclusive scan of 2048 bucket totals -> bucket_base[2049].
__global__ __launch_bounds__(256) void scan_base(
    const unsigned* __restrict__ totals,
    unsigned* __restrict__ bucket_base)
{
    __shared__ unsigned vals[NBK];
    __shared__ unsigned part[256];
    int t = threadIdx.x;
    #pragma unroll
    for (int j = 0; j < 8; ++j) vals[t * 8 + j] = totals[t * 8 + j];
    __syncthreads();
    unsigned s = 0;
    #pragma unroll
    for (int j = 0; j < 8; ++j) s += vals[t * 8 + j];
    part[t] = s;
    __syncthreads();
    for (int st = 1; st < 256; st <<= 1) {
        unsigned v = (t >= st) ? part[t - st] : 0u;
        __syncthreads();
        part[t] += v;
        __syncthreads();
    }
    unsigned base = (t == 0) ? 0u : part[t - 1];
    #pragma unroll
    for (int j = 0; j < 8; ++j) {
        unsigned v = vals[t * 8 + j];
        bucket_base[t * 8 + j] = base;
        base += v;
    }
    if (t == 255) bucket_base[NBK] = base;
}

__global__ __launch_bounds__(256) void scatter_atoms(
    const float* __restrict__ f_atom,
    const float* __restrict__ atom_pos,
    const int*   __restrict__ frag_id,
    const unsigned* __restrict__ histrows,
    const unsigned* __restrict__ bucket_base,
    float4*      __restrict__ recs,
    int n_atom)
{
    __shared__ unsigned hist[NBK];    // rank counters
    __shared__ unsigned obase[NBK];   // global start for this block per bucket
    int t = threadIdx.x;
    for (int b = t; b < NBK; b += 256) hist[b] = 0;
    __syncthreads();

    int bs = blockIdx.x * APB;
    unsigned rank[TILE];
    int fidv[TILE];
    #pragma unroll
    for (int j = 0; j < TILE; ++j) {
        int i = bs + j * 256 + t;
        if (i < n_atom) {
            int fid = frag_id[i];
            fidv[j] = fid;
            rank[j] = atomicAdd(&hist[fid / FPB], 1u);
        } else {
            fidv[j] = -1;
        }
    }
    // stage this block's exact offsets (coalesced reads)
    const unsigned* row = histrows + (size_t)blockIdx.x * NBK;
    for (int b = t; b < NBK; b += 256) obase[b] = row[b] + bucket_base[b];
    __syncthreads();

    #pragma unroll
    for (int j = 0; j < TILE; ++j) {
        int fid = fidv[j];
        if (fid < 0) continue;
        int i = bs + j * 256 + t;
        int bk = fid / FPB;
        int lf = fid - bk * FPB;
        unsigned pos = obase[bk] + rank[j];
        float px = atom_pos[3*i+0], py = atom_pos[3*i+1], pz = atom_pos[3*i+2];
        float fx = f_atom[3*i+0],  fy = f_atom[3*i+1],  fz = f_atom[3*i+2];
        recs[2*(size_t)pos + 0] = make_float4(px, py, pz, __int_as_float(lf));
        recs[2*(size_t)pos + 1] = make_float4(fx, fy, fz, 0.0f);
    }
}

__global__ __launch_bounds__(256) void sort_reduce(
    const float4*   __restrict__ recs,
    const unsigned* __restrict__ bucket_base,
    const float*    __restrict__ T_frag,
    const int*      __restrict__ frag_sizes,
    float*          __restrict__ out,
    int n_frag)
{
    __shared__ float    srt[CAP2 * 7];   // 63.6 KB, stride 7: all 32 banks hit
    __shared__ unsigned hist[FPB];
    __shared__ unsigned sc[128];
    __shared__ unsigned cbase[FPB];

    int b = blockIdx.x, t = threadIdx.x;
    int frag0 = b * FPB;
    int nf = n_frag - frag0;
    if (nf > FPB) nf = FPB;

    unsigned start = bucket_base[b];
    unsigned end   = bucket_base[b + 1];

    int g = t >> 1, h = t & 1;
    bool active = (t < 2 * nf);
    float Tx = 0, Ty = 0, Tz = 0;
    if (active) {
        int f = frag0 + g;
        Tx = T_frag[3*f+0]; Ty = T_frag[3*f+1]; Tz = T_frag[3*f+2];
    }
    float s[12];
    #pragma unroll
    for (int k = 0; k < 12; ++k) s[k] = 0.0f;
    unsigned fragcnt = 0;

    for (unsigned c0 = start; c0 < end; c0 += CAP2) {
        unsigned m = end - c0;
        if (m > CAP2) m = CAP2;

        for (int k = t; k < FPB; k += 256) hist[k] = 0;
        __syncthreads();

        float4 rv[MAXPT], fv[MAXPT];
        int rlf[MAXPT];
        unsigned rrk[MAXPT];
        #pragma unroll
        for (int k = 0; k < MAXPT; ++k) {
            unsigned i = (unsigned)t + (unsigned)k * 256u;
            rlf[k] = -1;
            if (i < m) {
                rv[k] = recs[2 * (size_t)(c0 + i) + 0];
                fv[k] = recs[2 * (size_t)(c0 + i) + 1];
                int lf = __float_as_int(rv[k].w);
                rlf[k] = lf;
                rrk[k] = atomicAdd(&hist[lf], 1u);
            }
        }
        __syncthreads();

        // parallel exclusive scan of hist -> cbase
        if (t < 128) sc[t] = (t < FPB) ? hist[t] : 0u;
        __syncthreads();
        #pragma unroll
        for (int st = 1; st < 128; st <<= 1) {
            unsigned v = 0;
            if (t < 128 && t >= st) v = sc[t - st];
            __syncthreads();
            if (t < 128) sc[t] += v;
            __syncthreads();
        }
        if (t < FPB) cbase[t] = sc[t] - hist[t];
        __syncthreads();

        // scatter into sorted slots, stride 7 (6 payload floats)
        #pragma unroll
        for (int k = 0; k < MAXPT; ++k) {
            if (rlf[k] >= 0) {
                unsigned p = (cbase[rlf[k]] + rrk[k]) * 7u;
                srt[p + 0] = rv[k].x; srt[p + 1] = rv[k].y; srt[p + 2] = rv[k].z;
                srt[p + 3] = fv[k].x; srt[p + 4] = fv[k].y; srt[p + 5] = fv[k].z;
            }
        }
        __syncthreads();

        // accumulate: 2 lanes per fragment over its contiguous run
        if (active) {
            unsigned cb = cbase[g], cc = hist[g];
            for (unsigned k = cb + h; k < cb + cc; k += 2) {
                const float* d = &srt[k * 7u];
                float rx = d[0] - Tx, ry = d[1] - Ty, rz = d[2] - Tz;
                float Fx = d[3], Fy = d[4], Fz = d[5];
                s[0] += Fx; s[1] += Fy; s[2] += Fz;
                s[3] += ry*Fz - rz*Fy;
                s[4] += rz*Fx - rx*Fz;
                s[5] += rx*Fy - ry*Fx;
                s[6] += rx*rx; s[7] += ry*ry; s[8] += rz*rz;
                s[9] += rx*ry; s[10] += rx*rz; s[11] += ry*rz;
            }
            if (h == 0) fragcnt += cc;
        }
        __syncthreads();
    }

    if (active) {
        #pragma unroll
        for (int k = 0; k < 12; ++k) s[k] += __shfl_xor(s[k], 1);
        if (h == 0) {
            float a[13];
            #pragma unroll
            for (int k = 0; k < 12; ++k) a[k] = s[k];
            a[12] = (float)fragcnt;
            frag_epilogue(a, frag0 + g, n_frag, frag_sizes, out);
        }
    }
}

// ===========================================================================
// FALLBACK: direct global f32 atomics (round-1, correctness-safe, any ws)
// ===========================================================================
#define NACC 16

__global__ __launch_bounds__(256) void atom_scatter_fb(
    const float* __restrict__ f_atom, const float* __restrict__ atom_pos,
    const float* __restrict__ T_frag, const int* __restrict__ frag_id,
    float* __restrict__ acc, int n_atom)
{
    int i = blockIdx.x * blockDim.x + threadIdx.x;
    if (i >= n_atom) return;
    int fid = frag_id[i];
    float fx = f_atom[3*i+0], fy = f_atom[3*i+1], fz = f_atom[3*i+2];
    float px = atom_pos[3*i+0], py = atom_pos[3*i+1], pz = atom_pos[3*i+2];
    float rx = px - T_frag[3*fid+0], ry = py - T_frag[3*fid+1], rz = pz - T_frag[3*fid+2];
    float cx = ry*fz - rz*fy, cy = rz*fx - rx*fz, cz = rx*fy - ry*fx;
    float* a = acc + (size_t)fid * NACC;
    atomicAdd(a+0, fx);    atomicAdd(a+1, fy);    atomicAdd(a+2, fz);
    atomicAdd(a+3, cx);    atomicAdd(a+4, cy);    atomicAdd(a+5, cz);
    atomicAdd(a+6, rx*rx); atomicAdd(a+7, ry*ry); atomicAdd(a+8, rz*rz);
    atomicAdd(a+9, rx*ry); atomicAdd(a+10, rx*rz); atomicAdd(a+11, ry*rz);
    atomicAdd(a+12, 1.0f);
}

__global__ __launch_bounds__(256) void frag_solve_fb(
    const float* __restrict__ acc, const int* __restrict__ frag_sizes,
    float* __restrict__ out, int n_frag)
{
    int f = blockIdx.x * blockDim.x + threadIdx.x;
    if (f >= n_frag) return;
    float a[13];
    #pragma unroll
    for (int k = 0; k < 13; ++k) a[k] = acc[(size_t)f * NACC + k];
    frag_epilogue(a, f, n_frag, frag_sizes, out);
}

extern "C" void kernel_launch(void* const* d_in, const int* in_sizes, int n_in,
                              void* d_out, int out_size, void* d_ws, size_t ws_size,
                              hipStream_t stream) {
    const float* f_atom     = (const float*)d_in[0];
    const float* atom_pos   = (const float*)d_in[1];
    const float* T_frag     = (const float*)d_in[2];
    const int*   frag_id    = (const int*)d_in[3];
    const int*   frag_sizes = (const int*)d_in[4];
    int n_atom = in_sizes[0] / 3;
    int n_frag = in_sizes[2] / 3;
    float* out = (float*)d_out;

    int nblk = (n_atom + APB - 1) / APB;          // 1954
    int nbk  = (n_frag + FPB - 1) / FPB;          // 2041

    size_t hist_bytes  = (size_t)nblk * NBK * sizeof(unsigned);   // ~16.0 MB
    size_t totals_off  = hist_bytes;
    size_t base_off    = totals_off + NBK * sizeof(unsigned);
    size_t recs_off    = (base_off + (NBK + 1) * sizeof(unsigned) + 255) & ~(size_t)255;
    size_t need        = recs_off + (size_t)n_atom * 2 * sizeof(float4);  // ~144.1 MB

    if (ws_size >= need && nbk <= NBK) {
        unsigned* histrows    = (unsigned*)d_ws;
        unsigned* totals      = (unsigned*)((char*)d_ws + totals_off);
        unsigned* bucket_base = (unsigned*)((char*)d_ws + base_off);
        float4*   recs        = (float4*)((char*)d_ws + recs_off);

        count_atoms<<<nblk, 256, 0, stream>>>(frag_id, histrows, n_atom);
        scan_cols<<<(NBK + 255) / 256, 256, 0, stream>>>(histrows, totals, nblk);
        scan_base<<<1, 256, 0, stream>>>(totals, bucket_base);
        scatter_atoms<<<nblk, 256, 0, stream>>>(
            f_atom, atom_pos, frag_id, histrows, bucket_base, recs, n_atom);
        sort_reduce<<<nbk, 256, 0, stream>>>(
            recs, bucket_base, T_frag, frag_sizes, out, n_frag);
    } else {
        float* acc = (float*)d_ws;
        hipMemsetAsync(acc, 0, (size_t)n_frag * NACC * sizeof(float), stream);
        atom_scatter_fb<<<(n_atom + 255) / 256, 256, 0, stream>>>(
            f_atom, atom_pos, T_frag, frag_id, acc, n_atom);
        frag_solve_fb<<<(n_frag + 255) / 256, 256, 0, stream>>>(acc, frag_sizes, out, n_frag);
    }
}

// Round 8
// 344.288 us; speedup vs baseline: 2.1995x; 2.1995x over previous
//
#include <hip/hip_runtime.h>
#include <math.h>

// ===========================================================================
// Shared epilogue: 3x3 symmetric Jacobi eigensolve (double) + output writes.
// acc layout (13 floats): [0..2]=sum f  [3..5]=sum r x f
//                         [6..11]=sum rr^T (xx,yy,zz,xy,xz,yz)  [12]=count
// ===========================================================================
__device__ __forceinline__ void frag_epilogue(
    const float* a, int f, int n_frag, const int* __restrict__ frag_sizes,
    float* __restrict__ out)
{
    float cntf  = a[12];
    float denom = fmaxf(cntf, 1.0f);
    float vfx = a[0] / denom, vfy = a[1] / denom, vfz = a[2] / denom;

    double tq0 = (double)a[3], tq1 = (double)a[4], tq2 = (double)a[5];
    double Mxx = (double)a[6], Myy = (double)a[7], Mzz = (double)a[8];
    double Mxy = (double)a[9], Mxz = (double)a[10], Myz = (double)a[11];
    double tr = Mxx + Myy + Mzz;

    double A[3][3] = {
        { tr - Mxx, -Mxy,     -Mxz     },
        { -Mxy,     tr - Myy, -Myz     },
        { -Mxz,     -Myz,     tr - Mzz }
    };
    double V[3][3] = {{1,0,0},{0,1,0},{0,0,1}};

    for (int sweep = 0; sweep < 6; ++sweep) {
        for (int pq = 0; pq < 3; ++pq) {
            int p = (pq == 2) ? 1 : 0;
            int q = (pq == 0) ? 1 : 2;
            double apq = A[p][q];
            if (fabs(apq) <= 1e-14 * (fabs(A[p][p]) + fabs(A[q][q])) ||
                fabs(apq) < 1e-300) continue;
            double theta = (A[q][q] - A[p][p]) / (2.0 * apq);
            double tt;
            if (fabs(theta) > 1e100) tt = 1.0 / (2.0 * theta);
            else tt = copysign(1.0, theta) / (fabs(theta) + sqrt(theta * theta + 1.0));
            double c = 1.0 / sqrt(tt * tt + 1.0);
            double s = tt * c;
            double app = A[p][p], aqq = A[q][q];
            A[p][p] = app - tt * apq;
            A[q][q] = aqq + tt * apq;
            A[p][q] = 0.0; A[q][p] = 0.0;
            int r = 3 - p - q;
            double arp = A[r][p], arq = A[r][q];
            A[r][p] = c * arp - s * arq; A[p][r] = A[r][p];
            A[r][q] = s * arp + c * arq; A[q][r] = A[r][q];
            for (int i2 = 0; i2 < 3; ++i2) {
                double vip = V[i2][p], viq = V[i2][q];
                V[i2][p] = c * vip - s * viq;
                V[i2][q] = s * vip + c * viq;
            }
        }
    }

    double lam0 = A[0][0], lam1 = A[1][1], lam2 = A[2][2];
    double maxeig = fmax(fmax(fmax(lam0, lam1), lam2), 1e-8);
    double thr = 0.01 * maxeig;
    bool small_frag = (frag_sizes[f] <= 1);
    double o0 = (!small_frag && lam0 > thr) ? 1.0 : 0.0;
    double o1 = (!small_frag && lam1 > thr) ? 1.0 : 0.0;
    double o2 = (!small_frag && lam2 > thr) ? 1.0 : 0.0;

    double te0 = V[0][0]*tq0 + V[1][0]*tq1 + V[2][0]*tq2;
    double te1 = V[0][1]*tq0 + V[1][1]*tq1 + V[2][1]*tq2;
    double te2 = V[0][2]*tq0 + V[1][2]*tq1 + V[2][2]*tq2;
    double we0 = te0 / fmax(lam0, 1e-6) * o0;
    double we1 = te1 / fmax(lam1, 1e-6) * o1;
    double we2 = te2 / fmax(lam2, 1e-6) * o2;
    double w0 = V[0][0]*we0 + V[0][1]*we1 + V[0][2]*we2;
    double w1 = V[1][0]*we0 + V[1][1]*we1 + V[1][2]*we2;
    double w2 = V[2][0]*we0 + V[2][1]*we1 + V[2][2]*we2;

    size_t F = (size_t)n_frag;
    out[(size_t)f*3 + 0] = vfx;
    out[(size_t)f*3 + 1] = vfy;
    out[(size_t)f*3 + 2] = vfz;
    out[F*3 + (size_t)f*3 + 0] = (float)w0;
    out[F*3 + (size_t)f*3 + 1] = (float)w1;
    out[F*3 + (size_t)f*3 + 2] = (float)w2;

    float* P = out + F*6 + (size_t)f*9;
    #pragma unroll
    for (int i2 = 0; i2 < 3; ++i2)
        #pragma unroll
        for (int k = 0; k < 3; ++k)
            P[i2*3 + k] = (float)(V[i2][0]*o0*V[k][0] + V[i2][1]*o1*V[k][1]
                                  + V[i2][2]*o2*V[k][2]);
}

// ===========================================================================
// FAST PATH (round 8): deterministic two-pass binning, zero global atomics.
// Round-7's scan_cols (454 µs! 2048 threads, 1954 serial dependent hops)
// replaced by a 3-pass blocked scan — fully coalesced, 128 blocks.
// ===========================================================================
#define NBK  2048            // bucket slots (used: nbk = ceil(F/98) = 2041)
#define FPB  98              // fragments per bucket
#define CAP2 2272            // LDS sort chunk capacity (records)
#define TILE 8
#define APB  (256 * TILE)    // 2048 atoms per bin block
#define MAXPT 9              // ceil(CAP2/256)
#define NCHUNK 16            // row-chunks for the blocked column scan

__global__ __launch_bounds__(256) void count_atoms(
    const int* __restrict__ frag_id,
    unsigned*  __restrict__ histrows,
    int n_atom)
{
    __shared__ unsigned hist[NBK];
    int t = threadIdx.x;
    for (int b = t; b < NBK; b += 256) hist[b] = 0;
    __syncthreads();
    int bs = blockIdx.x * APB;
    #pragma unroll
    for (int j = 0; j < TILE; ++j) {
        int i = bs + j * 256 + t;
        if (i < n_atom) atomicAdd(&hist[frag_id[i] / FPB], 1u);
    }
    __syncthreads();
    unsigned* row = histrows + (size_t)blockIdx.x * NBK;
    for (int b = t; b < NBK; b += 256) row[b] = hist[b];
}

// Pass 1: chunk sums. grid = (NBK/256, NCHUNK). Coalesced row reads.
__global__ __launch_bounds__(256) void scan_pass1(
    const unsigned* __restrict__ histrows,
    unsigned* __restrict__ chunksums,
    int nblk, int ch)
{
    int col = blockIdx.x * 256 + threadIdx.x;
    int c   = blockIdx.y;
    int r0 = c * ch, r1 = r0 + ch;
    if (r1 > nblk) r1 = nblk;
    unsigned s = 0;
    for (int r = r0; r < r1; ++r) s += histrows[(size_t)r * NBK + col];
    chunksums[(size_t)c * NBK + col] = s;
}

// Pass 2: exclusive scan of NCHUNK chunk sums per column; totals out.
__global__ __launch_bounds__(256) void scan_pass2(
    unsigned* __restrict__ chunksums,
    unsigned* __restrict__ totals)
{
    int col = blockIdx.x * 256 + threadIdx.x;
    unsigned cum = 0;
    #pragma unroll
    for (int c = 0; c < NCHUNK; ++c) {
        size_t idx = (size_t)c * NBK + col;
        unsigned v = chunksums[idx];
        chunksums[idx] = cum;
        cum += v;
    }
    totals[col] = cum;
}

// Pass 3: rewrite histrows in place with running per-column exclusive prefix.
__global__ __launch_bounds__(256) void scan_pass3(
    unsigned* __restrict__ histrows,
    const unsigned* __restrict__ chunksums,
    int nblk, int ch)
{
    int col = blockIdx.x * 256 + threadIdx.x;
    int c   = blockIdx.y;
    int r0 = c * ch, r1 = r0 + ch;
    if (r1 > nblk) r1 = nblk;
    unsigned cum = chunksums[(size_t)c * NBK + col];
    for (int r = r0; r < r1; ++r) {
        size_t idx = (size_t)r * NBK + col;
        unsigned v = histrows[idx];
        histrows[idx] = cum;
        cum += v;
    }
}

// Single block: exclusive scan of 2048 bucket totals -> bucket_base[2049].
__global__ __launch_bounds__(256) void scan_base(
    const unsigned* __restrict__ totals,
    unsigned* __restrict__ bucket_base)
{
    __shared__ unsigned vals[NBK];
    __shared__ unsigned part[256];
    int t = threadIdx.x;
    #pragma unroll
    for (int j = 0; j < 8; ++j) vals[t * 8 + j] = totals[t * 8 + j];
    __syncthreads();
    unsigned s = 0;
    #pragma unroll
    for (int j = 0; j < 8; ++j) s += vals[t * 8 + j];
    part[t] = s;
    __syncthreads();
    for (int st = 1; st < 256; st <<= 1) {
        unsigned v = (t >= st) ? part[t - st] : 0u;
        __syncthreads();
        part[t] += v;
        __syncthreads();
    }
    unsigned base = (t == 0) ? 0u : part[t - 1];
    #pragma unroll
    for (int j = 0; j < 8; ++j) {
        unsigned v = vals[t * 8 + j];
        bucket_base[t * 8 + j] = base;
        base += v;
    }
    if (t == 255) bucket_base[NBK] = base;
}

__global__ __launch_bounds__(256) void scatter_atoms(
    const float* __restrict__ f_atom,
    const float* __restrict__ atom_pos,
    const int*   __restrict__ frag_id,
    const unsigned* __restrict__ histrows,
    const unsigned* __restrict__ bucket_base,
    float4*      __restrict__ recs,
    int n_atom)
{
    __shared__ unsigned hist[NBK];    // rank counters
    __shared__ unsigned obase[NBK];   // global start for this block per bucket
    int t = threadIdx.x;
    for (int b = t; b < NBK; b += 256) hist[b] = 0;
    __syncthreads();

    int bs = blockIdx.x * APB;
    unsigned rank[TILE];
    int fidv[TILE];
    #pragma unroll
    for (int j = 0; j < TILE; ++j) {
        int i = bs + j * 256 + t;
        if (i < n_atom) {
            int fid = frag_id[i];
            fidv[j] = fid;
            rank[j] = atomicAdd(&hist[fid / FPB], 1u);
        } else {
            fidv[j] = -1;
        }
    }
    const unsigned* row = histrows + (size_t)blockIdx.x * NBK;
    for (int b = t; b < NBK; b += 256) obase[b] = row[b] + bucket_base[b];
    __syncthreads();

    #pragma unroll
    for (int j = 0; j < TILE; ++j) {
        int fid = fidv[j];
        if (fid < 0) continue;
        int i = bs + j * 256 + t;
        int bk = fid / FPB;
        int lf = fid - bk * FPB;
        unsigned pos = obase[bk] + rank[j];
        float px = atom_pos[3*i+0], py = atom_pos[3*i+1], pz = atom_pos[3*i+2];
        float fx = f_atom[3*i+0],  fy = f_atom[3*i+1],  fz = f_atom[3*i+2];
        recs[2*(size_t)pos + 0] = make_float4(px, py, pz, __int_as_float(lf));
        recs[2*(size_t)pos + 1] = make_float4(fx, fy, fz, 0.0f);
    }
}

__global__ __launch_bounds__(256) void sort_reduce(
    const float4*   __restrict__ recs,
    const unsigned* __restrict__ bucket_base,
    const float*    __restrict__ T_frag,
    const int*      __restrict__ frag_sizes,
    float*          __restrict__ out,
    int n_frag)
{
    __shared__ float    srt[CAP2 * 7];   // 63.6 KB, stride 7: all 32 banks hit
    __shared__ unsigned hist[FPB];
    __shared__ unsigned sc[128];
    __shared__ unsigned cbase[FPB];

    int b = blockIdx.x, t = threadIdx.x;
    int frag0 = b * FPB;
    int nf = n_frag - frag0;
    if (nf > FPB) nf = FPB;

    unsigned start = bucket_base[b];
    unsigned end   = bucket_base[b + 1];

    int g = t >> 1, h = t & 1;
    bool active = (t < 2 * nf);
    float Tx = 0, Ty = 0, Tz = 0;
    if (active) {
        int f = frag0 + g;
        Tx = T_frag[3*f+0]; Ty = T_frag[3*f+1]; Tz = T_frag[3*f+2];
    }
    float s[12];
    #pragma unroll
    for (int k = 0; k < 12; ++k) s[k] = 0.0f;
    unsigned fragcnt = 0;

    for (unsigned c0 = start; c0 < end; c0 += CAP2) {
        unsigned m = end - c0;
        if (m > CAP2) m = CAP2;

        for (int k = t; k < FPB; k += 256) hist[k] = 0;
        __syncthreads();

        float4 rv[MAXPT], fv[MAXPT];
        int rlf[MAXPT];
        unsigned rrk[MAXPT];
        #pragma unroll
        for (int k = 0; k < MAXPT; ++k) {
            unsigned i = (unsigned)t + (unsigned)k * 256u;
            rlf[k] = -1;
            if (i < m) {
                rv[k] = recs[2 * (size_t)(c0 + i) + 0];
                fv[k] = recs[2 * (size_t)(c0 + i) + 1];
                int lf = __float_as_int(rv[k].w);
                rlf[k] = lf;
                rrk[k] = atomicAdd(&hist[lf], 1u);
            }
        }
        __syncthreads();

        if (t < 128) sc[t] = (t < FPB) ? hist[t] : 0u;
        __syncthreads();
        #pragma unroll
        for (int st = 1; st < 128; st <<= 1) {
            unsigned v = 0;
            if (t < 128 && t >= st) v = sc[t - st];
            __syncthreads();
            if (t < 128) sc[t] += v;
            __syncthreads();
        }
        if (t < FPB) cbase[t] = sc[t] - hist[t];
        __syncthreads();

        #pragma unroll
        for (int k = 0; k < MAXPT; ++k) {
            if (rlf[k] >= 0) {
                unsigned p = (cbase[rlf[k]] + rrk[k]) * 7u;
                srt[p + 0] = rv[k].x; srt[p + 1] = rv[k].y; srt[p + 2] = rv[k].z;
                srt[p + 3] = fv[k].x; srt[p + 4] = fv[k].y; srt[p + 5] = fv[k].z;
            }
        }
        __syncthreads();

        if (active) {
            unsigned cb = cbase[g], cc = hist[g];
            for (unsigned k = cb + h; k < cb + cc; k += 2) {
                const float* d = &srt[k * 7u];
                float rx = d[0] - Tx, ry = d[1] - Ty, rz = d[2] - Tz;
                float Fx = d[3], Fy = d[4], Fz = d[5];
                s[0] += Fx; s[1] += Fy; s[2] += Fz;
                s[3] += ry*Fz - rz*Fy;
                s[4] += rz*Fx - rx*Fz;
                s[5] += rx*Fy - ry*Fx;
                s[6] += rx*rx; s[7] += ry*ry; s[8] += rz*rz;
                s[9] += rx*ry; s[10] += rx*rz; s[11] += ry*rz;
            }
            if (h == 0) fragcnt += cc;
        }
        __syncthreads();
    }

    if (active) {
        #pragma unroll
        for (int k = 0; k < 12; ++k) s[k] += __shfl_xor(s[k], 1);
        if (h == 0) {
            float a[13];
            #pragma unroll
            for (int k = 0; k < 12; ++k) a[k] = s[k];
            a[12] = (float)fragcnt;
            frag_epilogue(a, frag0 + g, n_frag, frag_sizes, out);
        }
    }
}

// ===========================================================================
// FALLBACK: direct global f32 atomics (round-1, correctness-safe, any ws)
// ===========================================================================
#define NACC 16

__global__ __launch_bounds__(256) void atom_scatter_fb(
    const float* __restrict__ f_atom, const float* __restrict__ atom_pos,
    const float* __restrict__ T_frag, const int* __restrict__ frag_id,
    float* __restrict__ acc, int n_atom)
{
    int i = blockIdx.x * blockDim.x + threadIdx.x;
    if (i >= n_atom) return;
    int fid = frag_id[i];
    float fx = f_atom[3*i+0], fy = f_atom[3*i+1], fz = f_atom[3*i+2];
    float px = atom_pos[3*i+0], py = atom_pos[3*i+1], pz = atom_pos[3*i+2];
    float rx = px - T_frag[3*fid+0], ry = py - T_frag[3*fid+1], rz = pz - T_frag[3*fid+2];
    float cx = ry*fz - rz*fy, cy = rz*fx - rx*fz, cz = rx*fy - ry*fx;
    float* a = acc + (size_t)fid * NACC;
    atomicAdd(a+0, fx);    atomicAdd(a+1, fy);    atomicAdd(a+2, fz);
    atomicAdd(a+3, cx);    atomicAdd(a+4, cy);    atomicAdd(a+5, cz);
    atomicAdd(a+6, rx*rx); atomicAdd(a+7, ry*ry); atomicAdd(a+8, rz*rz);
    atomicAdd(a+9, rx*ry); atomicAdd(a+10, rx*rz); atomicAdd(a+11, ry*rz);
    atomicAdd(a+12, 1.0f);
}

__global__ __launch_bounds__(256) void frag_solve_fb(
    const float* __restrict__ acc, const int* __restrict__ frag_sizes,
    float* __restrict__ out, int n_frag)
{
    int f = blockIdx.x * blockDim.x + threadIdx.x;
    if (f >= n_frag) return;
    float a[13];
    #pragma unroll
    for (int k = 0; k < 13; ++k) a[k] = acc[(size_t)f * NACC + k];
    frag_epilogue(a, f, n_frag, frag_sizes, out);
}

extern "C" void kernel_launch(void* const* d_in, const int* in_sizes, int n_in,
                              void* d_out, int out_size, void* d_ws, size_t ws_size,
                              hipStream_t stream) {
    const float* f_atom     = (const float*)d_in[0];
    const float* atom_pos   = (const float*)d_in[1];
    const float* T_frag     = (const float*)d_in[2];
    const int*   frag_id    = (const int*)d_in[3];
    const int*   frag_sizes = (const int*)d_in[4];
    int n_atom = in_sizes[0] / 3;
    int n_frag = in_sizes[2] / 3;
    float* out = (float*)d_out;

    int nblk = (n_atom + APB - 1) / APB;          // 1954
    int nbk  = (n_frag + FPB - 1) / FPB;          // 2041
    int ch   = (nblk + NCHUNK - 1) / NCHUNK;      // 123 rows per chunk

    size_t hist_bytes = (size_t)nblk * NBK * sizeof(unsigned);        // ~16.0 MB
    size_t cs_off     = hist_bytes;
    size_t tot_off    = cs_off + (size_t)NCHUNK * NBK * sizeof(unsigned);
    size_t base_off   = tot_off + NBK * sizeof(unsigned);
    size_t recs_off   = (base_off + (NBK + 1) * sizeof(unsigned) + 255) & ~(size_t)255;
    size_t need       = recs_off + (size_t)n_atom * 2 * sizeof(float4);  // ~144.3 MB

    if (ws_size >= need && nbk <= NBK) {
        unsigned* histrows    = (unsigned*)d_ws;
        unsigned* chunksums   = (unsigned*)((char*)d_ws + cs_off);
        unsigned* totals      = (unsigned*)((char*)d_ws + tot_off);
        unsigned* bucket_base = (unsigned*)((char*)d_ws + base_off);
        float4*   recs        = (float4*)((char*)d_ws + recs_off);

        count_atoms<<<nblk, 256, 0, stream>>>(frag_id, histrows, n_atom);
        dim3 sgrid(NBK / 256, NCHUNK);
        scan_pass1<<<sgrid, 256, 0, stream>>>(histrows, chunksums, nblk, ch);
        scan_pass2<<<NBK / 256, 256, 0, stream>>>(chunksums, totals);
        scan_base<<<1, 256, 0, stream>>>(totals, bucket_base);
        scan_pass3<<<sgrid, 256, 0, stream>>>(histrows, chunksums, nblk, ch);
        scatter_atoms<<<nblk, 256, 0, stream>>>(
            f_atom, atom_pos, frag_id, histrows, bucket_base, recs, n_atom);
        sort_reduce<<<nbk, 256, 0, stream>>>(
            recs, bucket_base, T_frag, frag_sizes, out, n_frag);
    } else {
        float* acc = (float*)d_ws;
        hipMemsetAsync(acc, 0, (size_t)n_frag * NACC * sizeof(float), stream);
        atom_scatter_fb<<<(n_atom + 255) / 256, 256, 0, stream>>>(
            f_atom, atom_pos, T_frag, frag_id, acc, n_atom);
        frag_solve_fb<<<(n_frag + 255) / 256, 256, 0, stream>>>(acc, frag_sizes, out, n_frag);
    }
}